// Round 2
// baseline (307.079 us; speedup 1.0000x reference)
//
#include <hip/hip_runtime.h>
#include <stdint.h>

#define L_SEQ 256
#define E_DIM 64
#define N_B   64
#define LN_EPS 1e-5f

typedef float f4 __attribute__((ext_vector_type(4)));

// ---------------------------------------------------------------------------
// Kernel A: per (n, a-chunk of 16 rows): energy[a,b] = sum_l Q[n,l,a]*K[n,l,b],
// softmax over b, write attn TRANSPOSED to ws: wsAttn[n][b][a]  (f32, 1 MiB).
// 256 blocks x 64 threads. LDS: Q-chunk 16 KB + K 64 KB.
// ---------------------------------------------------------------------------
__global__ __launch_bounds__(64) void attn_softmax_kernel(
    const float* __restrict__ gq,
    const float* __restrict__ gk,
    float* __restrict__ wsAttn)
{
    __shared__ float Qs[L_SEQ][16];
    __shared__ float Ks[L_SEQ][E_DIM];

    const int t  = threadIdx.x;
    const int n  = blockIdx.x >> 2;
    const int ac = blockIdx.x & 3;          // a-chunk: rows [ac*16, ac*16+16)

    const float* qb = gq + (size_t)n * (L_SEQ * E_DIM);
    const float* kb = gk + (size_t)n * (L_SEQ * E_DIM);

    // stage K (256x64 f32): 4096 float4 packs, 64 per thread
    #pragma unroll 8
    for (int i = 0; i < 64; ++i) {
        int idx4 = t + 64 * i;
        int l = idx4 >> 4, c = (idx4 & 15) * 4;
        *reinterpret_cast<f4*>(&Ks[l][c]) =
            *reinterpret_cast<const f4*>(kb + (size_t)idx4 * 4);
    }
    // stage Q chunk (256x16): 1024 float4 packs, 16 per thread
    #pragma unroll 8
    for (int i = 0; i < 16; ++i) {
        int idx4 = t + 64 * i;
        int l = idx4 >> 2, c = (idx4 & 3) * 4;
        *reinterpret_cast<f4*>(&Qs[l][c]) =
            *reinterpret_cast<const f4*>(qb + (size_t)l * E_DIM + ac * 16 + c);
    }
    __syncthreads();

    const int tx = t & 15, ty = t >> 4;     // 16 b-tiles x 4 a-tiles
    const int b0 = tx * 4, a0 = ty * 4;

    float acc[4][4] = {};                   // [ia][ib]
    #pragma unroll 8
    for (int l = 0; l < L_SEQ; ++l) {
        f4 qa = *reinterpret_cast<const f4*>(&Qs[l][a0]);
        f4 kv = *reinterpret_cast<const f4*>(&Ks[l][b0]);
        #pragma unroll
        for (int ia = 0; ia < 4; ++ia)
            #pragma unroll
            for (int ib = 0; ib < 4; ++ib)
                acc[ia][ib] = fmaf(qa[ia], kv[ib], acc[ia][ib]);
    }

    // softmax over b (spread across the 16 tx lanes; xor<=8 stays in group).
    // hd==1 -> 1/sqrt(hd) is identity.
    #pragma unroll
    for (int ia = 0; ia < 4; ++ia) {
        float m = fmaxf(fmaxf(acc[ia][0], acc[ia][1]),
                        fmaxf(acc[ia][2], acc[ia][3]));
        #pragma unroll
        for (int s = 1; s <= 8; s <<= 1) m = fmaxf(m, __shfl_xor(m, s));
        float e0 = __expf(acc[ia][0] - m);
        float e1 = __expf(acc[ia][1] - m);
        float e2 = __expf(acc[ia][2] - m);
        float e3 = __expf(acc[ia][3] - m);
        float ssum = (e0 + e1) + (e2 + e3);
        #pragma unroll
        for (int s = 1; s <= 8; s <<= 1) ssum += __shfl_xor(ssum, s);
        float inv = 1.0f / ssum;
        acc[ia][0] = e0 * inv; acc[ia][1] = e1 * inv;
        acc[ia][2] = e2 * inv; acc[ia][3] = e3 * inv;
    }

    // write transposed: wsAttn[n*4096 + b*64 + a], a contiguous
    float* wbase = wsAttn + n * 4096 + ac * 16 + a0;
    #pragma unroll
    for (int ib = 0; ib < 4; ++ib) {
        f4 v4 = {acc[0][ib], acc[1][ib], acc[2][ib], acc[3][ib]};
        *reinterpret_cast<f4*>(wbase + (size_t)(b0 + ib) * 64) = v4;
    }
}

// ---------------------------------------------------------------------------
// Kernel B: per (n, l-chunk of 64):
//   T[l][j]  = sum_k attn[j,n,k] * values[k, l0+l, n]
//   fc[l][e] = sum_j T[l][j] * W_out[e][j] + b_out[e]
//   LN over e (the +query residual is constant over e -> cancels), then
//   broadcast-store the 64x64 f32 tile to all 64 h slices.
// 256 blocks x 256 threads. LDS ~66 KB.
// ---------------------------------------------------------------------------
__global__ __launch_bounds__(256) void out_ln_kernel(
    const float* __restrict__ gv,
    const float* __restrict__ gw,
    const float* __restrict__ gbo,
    const float* __restrict__ glnw,
    const float* __restrict__ glnb,
    const float* __restrict__ wsAttn,
    float*       __restrict__ gout)
{
    __shared__ float At[64][64];    // At[k][j] = attn[j,n,k]
    __shared__ float Vs[64][64];    // Vs[k][l_local]
    __shared__ float Wt[64][68];    // Wt[j][e] = W_out[e][j] (pad 68 keeps rows 16B-aligned)
    __shared__ float Tt[64][64];    // Tt[j][l_local]

    const int t  = threadIdx.x;
    const int n  = blockIdx.x >> 2;
    const int lc = blockIdx.x & 3;
    const int l0 = lc * 64;

    // attn^T tile: 4096 f32, coalesced float4
    const f4* asrc = reinterpret_cast<const f4*>(wsAttn + n * 4096);
    f4* adst = reinterpret_cast<f4*>(&At[0][0]);
    #pragma unroll
    for (int i = 0; i < 4; ++i) adst[t + 256 * i] = asrc[t + 256 * i];

    // V slice (strided gather): Vs[k][ll] = values[k, l0+ll, n]
    #pragma unroll 4
    for (int i = 0; i < 16; ++i) {
        int idx = t + 256 * i;
        int k = idx >> 6, ll = idx & 63;
        Vs[k][ll] = gv[(size_t)k * (L_SEQ * E_DIM) + (size_t)(l0 + ll) * E_DIM + n];
    }
    // W^T: Wt[j][e] = W_out[e*64 + j]  (global read coalesced)
    #pragma unroll 4
    for (int i = 0; i < 16; ++i) {
        int idx = t + 256 * i;
        int e = idx >> 6, j = idx & 63;
        Wt[j][e] = gw[idx];
    }
    __syncthreads();

    const int tx = t & 15, ty = t >> 4;

    // GEMM1: tile l = 4*tx.., j = 4*ty..
    float Ta[4][4] = {};            // [jj][ll]
    #pragma unroll 8
    for (int k = 0; k < 64; ++k) {
        f4 a4 = *reinterpret_cast<const f4*>(&At[k][ty * 4]);
        f4 v4 = *reinterpret_cast<const f4*>(&Vs[k][tx * 4]);
        #pragma unroll
        for (int jj = 0; jj < 4; ++jj)
            #pragma unroll
            for (int ll = 0; ll < 4; ++ll)
                Ta[jj][ll] = fmaf(a4[jj], v4[ll], Ta[jj][ll]);
    }
    #pragma unroll
    for (int jj = 0; jj < 4; ++jj) {
        f4 w4 = {Ta[jj][0], Ta[jj][1], Ta[jj][2], Ta[jj][3]};
        *reinterpret_cast<f4*>(&Tt[ty * 4 + jj][tx * 4]) = w4;
    }
    __syncthreads();

    // GEMM2: tile l = 4*ty.., e = 4*tx..
    float fc[4][4] = {};            // [il][ie]
    #pragma unroll 8
    for (int j = 0; j < 64; ++j) {
        f4 t4 = *reinterpret_cast<const f4*>(&Tt[j][ty * 4]);
        f4 w4 = *reinterpret_cast<const f4*>(&Wt[j][tx * 4]);
        #pragma unroll
        for (int il = 0; il < 4; ++il)
            #pragma unroll
            for (int ie = 0; ie < 4; ++ie)
                fc[il][ie] = fmaf(t4[il], w4[ie], fc[il][ie]);
    }

    float be[4], lw[4], lb[4];
    #pragma unroll
    for (int ie = 0; ie < 4; ++ie) {
        be[ie] = gbo[tx * 4 + ie];
        lw[ie] = glnw[tx * 4 + ie];
        lb[ie] = glnb[tx * 4 + ie];
    }

    // LayerNorm per l-row; row spread over the 16 tx lanes (same wave).
    f4 o4[4];
    #pragma unroll
    for (int il = 0; il < 4; ++il) {
        float v0 = fc[il][0] + be[0];
        float v1 = fc[il][1] + be[1];
        float v2 = fc[il][2] + be[2];
        float v3 = fc[il][3] + be[3];
        float s1 = (v0 + v1) + (v2 + v3);
        float s2 = (v0 * v0 + v1 * v1) + (v2 * v2 + v3 * v3);
        #pragma unroll
        for (int s = 1; s <= 8; s <<= 1) {
            s1 += __shfl_xor(s1, s);
            s2 += __shfl_xor(s2, s);
        }
        float mu  = s1 * (1.0f / 64.0f);
        float var = s2 * (1.0f / 64.0f) - mu * mu;
        float rs  = rsqrtf(var + LN_EPS);
        o4[il][0] = (v0 - mu) * rs * lw[0] + lb[0];
        o4[il][1] = (v1 - mu) * rs * lw[1] + lb[1];
        o4[il][2] = (v2 - mu) * rs * lw[2] + lb[2];
        o4[il][3] = (v3 - mu) * rs * lw[3] + lb[3];
    }

    // Broadcast-store to all 64 h slices (output independent of h).
    const size_t slice = (size_t)N_B * L_SEQ * E_DIM;   // 1,048,576 elems per h
    float* obase = gout + (size_t)n * (L_SEQ * E_DIM)
                        + (size_t)(l0 + ty * 4) * E_DIM + tx * 4;
    #pragma unroll 4
    for (int h = 0; h < 64; ++h) {
        float* op = obase + (size_t)h * slice;
        #pragma unroll
        for (int il = 0; il < 4; ++il)
            __builtin_nontemporal_store(
                o4[il], reinterpret_cast<f4*>(op + (size_t)il * E_DIM));
    }
}

extern "C" void kernel_launch(void* const* d_in, const int* in_sizes, int n_in,
                              void* d_out, int out_size, void* d_ws, size_t ws_size,
                              hipStream_t stream)
{
    const float* gv  = (const float*)d_in[0];  // values  [N,L,E] f32
    const float* gk  = (const float*)d_in[1];  // keys    [N,L,E]
    const float* gq  = (const float*)d_in[2];  // query   [N,L,E]
    const float* gw  = (const float*)d_in[3];  // W_out   [E,E]
    const float* gbo = (const float*)d_in[4];  // b_out   [E]
    const float* glw = (const float*)d_in[5];  // ln_w    [E]
    const float* glb = (const float*)d_in[6];  // ln_b    [E]
    float* wsAttn = (float*)d_ws;              // 64*64*64 f32 = 1 MiB scratch
    float* out    = (float*)d_out;             // [H,N,L,E] f32

    hipLaunchKernelGGL(attn_softmax_kernel, dim3(256), dim3(64), 0, stream,
                       gq, gk, wsAttn);
    hipLaunchKernelGGL(out_ln_kernel, dim3(256), dim3(256), 0, stream,
                       gv, gw, gbo, glw, glb, wsAttn, out);
}

// Round 3
// 306.032 us; speedup vs baseline: 1.0034x; 1.0034x over previous
//
#include <hip/hip_runtime.h>
#include <stdint.h>

#define L_SEQ 256
#define E_DIM 64
#define N_B   64
#define LN_EPS 1e-5f

typedef float f4 __attribute__((ext_vector_type(4)));

// ---------------------------------------------------------------------------
// Kernel A: one block per n (grid 64 x 256 threads, 4 waves/CU).
//   energy[a,b] = sum_l Q[n,l,a]*K[n,l,b]; softmax over b;
//   ws[n*4096 + b*64 + a] = attn[a,n,b]        (f32, 1 MiB total)
// LDS: full Q tile + full K tile = 128 KB (gfx950 has 160 KB/CU).
// ---------------------------------------------------------------------------
__global__ __launch_bounds__(256) void attn_softmax_kernel(
    const float* __restrict__ gq,
    const float* __restrict__ gk,
    float* __restrict__ ws)
{
    __shared__ float Qs[L_SEQ * E_DIM];   // [l][a], 64 KB
    __shared__ float Ks[L_SEQ * E_DIM];   // [l][b], 64 KB

    const int t = threadIdx.x;
    const int n = blockIdx.x;
    const float* qb = gq + (size_t)n * (L_SEQ * E_DIM);
    const float* kb = gk + (size_t)n * (L_SEQ * E_DIM);

    // flat coalesced f4 copies: 4096 f4 per tile, 16 per thread each
    #pragma unroll
    for (int i = 0; i < 16; ++i) {
        reinterpret_cast<f4*>(Qs)[t + 256 * i] =
            reinterpret_cast<const f4*>(qb)[t + 256 * i];
        reinterpret_cast<f4*>(Ks)[t + 256 * i] =
            reinterpret_cast<const f4*>(kb)[t + 256 * i];
    }
    __syncthreads();

    const int tx = t & 15, ty = t >> 4;   // tx -> b-tile, ty -> a-tile
    const int b0 = tx * 4, a0 = ty * 4;

    float acc[4][4] = {};                 // [ia][ib]
    #pragma unroll 8
    for (int l = 0; l < L_SEQ; ++l) {
        f4 qa = *reinterpret_cast<const f4*>(&Qs[l * E_DIM + a0]);
        f4 kv = *reinterpret_cast<const f4*>(&Ks[l * E_DIM + b0]);
        #pragma unroll
        for (int ia = 0; ia < 4; ++ia)
            #pragma unroll
            for (int ib = 0; ib < 4; ++ib)
                acc[ia][ib] = fmaf(qa[ia], kv[ib], acc[ia][ib]);
    }

    // softmax over b; row a0+ia is spread over the 16 tx lanes (bits 0-3 of
    // the lane id, so xor<=8 stays inside the group). hd==1 -> no scale.
    #pragma unroll
    for (int ia = 0; ia < 4; ++ia) {
        float m = fmaxf(fmaxf(acc[ia][0], acc[ia][1]),
                        fmaxf(acc[ia][2], acc[ia][3]));
        #pragma unroll
        for (int s = 1; s <= 8; s <<= 1) m = fmaxf(m, __shfl_xor(m, s));
        float e0 = __expf(acc[ia][0] - m);
        float e1 = __expf(acc[ia][1] - m);
        float e2 = __expf(acc[ia][2] - m);
        float e3 = __expf(acc[ia][3] - m);
        float ssum = (e0 + e1) + (e2 + e3);
        #pragma unroll
        for (int s = 1; s <= 8; s <<= 1) ssum += __shfl_xor(ssum, s);
        float inv = 1.0f / ssum;
        acc[ia][0] = e0 * inv; acc[ia][1] = e1 * inv;
        acc[ia][2] = e2 * inv; acc[ia][3] = e3 * inv;
    }

    // ws[n][b][a], a contiguous. NOT nontemporal: we want ws hot in L2 for B.
    float* wbase = ws + n * 4096 + a0;
    #pragma unroll
    for (int ib = 0; ib < 4; ++ib) {
        f4 v4 = {acc[0][ib], acc[1][ib], acc[2][ib], acc[3][ib]};
        *reinterpret_cast<f4*>(wbase + (size_t)(b0 + ib) * 64) = v4;
    }
}

// ---------------------------------------------------------------------------
// Kernel B: one block per l (grid 256 x 256 threads).
//   T[n][j]  = sum_k attn[j,n,k] * V[k,l,n]      (ws re-read: L2/L3 resident)
//   fc[n][e] = sum_j T[n][j] * W_out[e][j] + b_out[e]
//   LN over e (the +query residual is constant over e -> cancels), then
//   broadcast-store row [n][l][0:64] to all 64 h slices (output h-independent).
// V staging is now COALESCED: values[k, l, 0:64] are contiguous 256 B rows.
// ---------------------------------------------------------------------------
__global__ __launch_bounds__(256) void out_ln_kernel(
    const float* __restrict__ gv,
    const float* __restrict__ gw,
    const float* __restrict__ gbo,
    const float* __restrict__ glnw,
    const float* __restrict__ glnb,
    const float* __restrict__ ws,
    float*       __restrict__ gout)
{
    __shared__ float Vl[E_DIM * N_B];   // [k][n], 16 KB
    __shared__ float Wt[64 * 68];       // [j][e], pad 68 (rows 16B-aligned)
    __shared__ float Tt[64 * 64];       // [n][j], 16 KB

    const int t = threadIdx.x;
    const int l = blockIdx.x;

    // Vl[k][n] = values[k, l, n] — contiguous rows of 64 floats
    #pragma unroll
    for (int i = 0; i < 4; ++i) {
        int idx4 = t + 256 * i;                // f4 index
        int k = idx4 >> 4, c = (idx4 & 15) * 4;
        reinterpret_cast<f4*>(Vl)[idx4] =
            *reinterpret_cast<const f4*>(gv + (size_t)k * (L_SEQ * E_DIM)
                                            + (size_t)l * E_DIM + c);
    }
    // Wt[j][e] = W_out[e*64 + j] (global read coalesced)
    #pragma unroll
    for (int i = 0; i < 16; ++i) {
        int idx = t + 256 * i;
        int e = idx >> 6, j = idx & 63;
        Wt[j * 68 + e] = gw[idx];
    }
    __syncthreads();

    const int tx = t & 15, tg = t >> 4;
    const int j0 = tx * 4;          // 4 j's per thread
    const int n0 = tg * 4;          // 4 n's per thread

    // T[in][jj] = sum_k ws[n0+in][k][j0+jj] * Vl[k][n0+in]
    // ws loads: lanes cover ws[n][k][0:64] = 256 B segments, 4 n-groups/wave.
    float T[4][4] = {};
    #pragma unroll 4
    for (int k = 0; k < 64; ++k) {
        f4 vk = *reinterpret_cast<const f4*>(&Vl[k * 64 + n0]);
        #pragma unroll
        for (int in = 0; in < 4; ++in) {
            f4 a4 = *reinterpret_cast<const f4*>(
                ws + (size_t)(n0 + in) * 4096 + k * 64 + j0);
            #pragma unroll
            for (int jj = 0; jj < 4; ++jj)
                T[in][jj] = fmaf(a4[jj], vk[in], T[in][jj]);
        }
    }
    #pragma unroll
    for (int in = 0; in < 4; ++in) {
        f4 w4 = {T[in][0], T[in][1], T[in][2], T[in][3]};
        *reinterpret_cast<f4*>(&Tt[(n0 + in) * 64 + j0]) = w4;
    }
    __syncthreads();

    // fc[in][ie] = sum_j Tt[n0+in][j] * Wt[j][e0+ie]
    const int e0 = tx * 4;
    float fc[4][4] = {};
    #pragma unroll 4
    for (int jj = 0; jj < 64; jj += 4) {
        f4 t4[4];
        #pragma unroll
        for (int in = 0; in < 4; ++in)
            t4[in] = *reinterpret_cast<const f4*>(&Tt[(n0 + in) * 64 + jj]);
        #pragma unroll
        for (int m = 0; m < 4; ++m) {
            f4 w4 = *reinterpret_cast<const f4*>(&Wt[(jj + m) * 68 + e0]);
            #pragma unroll
            for (int in = 0; in < 4; ++in)
                #pragma unroll
                for (int ie = 0; ie < 4; ++ie)
                    fc[in][ie] = fmaf(t4[in][m], w4[ie], fc[in][ie]);
        }
    }

    float be[4], lw[4], lb[4];
    #pragma unroll
    for (int ie = 0; ie < 4; ++ie) {
        be[ie] = gbo[e0 + ie];
        lw[ie] = glnw[e0 + ie];
        lb[ie] = glnb[e0 + ie];
    }

    // LayerNorm per n-row; row spread over the 16 tx lanes (same wave).
    f4 o4[4];
    #pragma unroll
    for (int in = 0; in < 4; ++in) {
        float v0 = fc[in][0] + be[0];
        float v1 = fc[in][1] + be[1];
        float v2 = fc[in][2] + be[2];
        float v3 = fc[in][3] + be[3];
        float s1 = (v0 + v1) + (v2 + v3);
        float s2 = (v0 * v0 + v1 * v1) + (v2 * v2 + v3 * v3);
        #pragma unroll
        for (int s = 1; s <= 8; s <<= 1) {
            s1 += __shfl_xor(s1, s);
            s2 += __shfl_xor(s2, s);
        }
        float mu  = s1 * (1.0f / 64.0f);
        float var = s2 * (1.0f / 64.0f) - mu * mu;
        float rs  = rsqrtf(var + LN_EPS);
        o4[in][0] = (v0 - mu) * rs * lw[0] + lb[0];
        o4[in][1] = (v1 - mu) * rs * lw[1] + lb[1];
        o4[in][2] = (v2 - mu) * rs * lw[2] + lb[2];
        o4[in][3] = (v3 - mu) * rs * lw[3] + lb[3];
    }

    // Broadcast-store to all 64 h slices. out[h][n][l][e].
    const size_t hstride = (size_t)N_B * L_SEQ * E_DIM;   // 1,048,576 floats
    float* ob0 = gout + (size_t)n0 * (L_SEQ * E_DIM) + (size_t)l * E_DIM + e0;
    #pragma unroll 8
    for (int h = 0; h < 64; ++h) {
        float* op = ob0 + (size_t)h * hstride;
        #pragma unroll
        for (int in = 0; in < 4; ++in)
            __builtin_nontemporal_store(
                o4[in], reinterpret_cast<f4*>(op + (size_t)in * (L_SEQ * E_DIM)));
    }
}

extern "C" void kernel_launch(void* const* d_in, const int* in_sizes, int n_in,
                              void* d_out, int out_size, void* d_ws, size_t ws_size,
                              hipStream_t stream)
{
    const float* gv  = (const float*)d_in[0];  // values  [N,L,E] f32
    const float* gk  = (const float*)d_in[1];  // keys    [N,L,E]
    const float* gq  = (const float*)d_in[2];  // query   [N,L,E]
    const float* gw  = (const float*)d_in[3];  // W_out   [E,E]
    const float* gbo = (const float*)d_in[4];  // b_out   [E]
    const float* glw = (const float*)d_in[5];  // ln_w    [E]
    const float* glb = (const float*)d_in[6];  // ln_b    [E]
    float* wsAttn = (float*)d_ws;              // 64*64*64 f32 = 1 MiB scratch
    float* out    = (float*)d_out;             // [H,N,L,E] f32

    hipLaunchKernelGGL(attn_softmax_kernel, dim3(64), dim3(256), 0, stream,
                       gq, gk, wsAttn);
    hipLaunchKernelGGL(out_ln_kernel, dim3(256), dim3(256), 0, stream,
                       gv, gw, gbo, glw, glb, wsAttn, out);
}